// Round 2
// baseline (546.140 us; speedup 1.0000x reference)
//
#include <hip/hip_runtime.h>
#include <hip/hip_bf16.h>
#include <stdint.h>

#define IN_F 4096
#define OUT_F 4096
#define MTOK 8192
#define TOPX_N 10
#define NUMVALS 200000

typedef __bf16 bf16x8 __attribute__((ext_vector_type(8)));
typedef float f32x4 __attribute__((ext_vector_type(4)));

__device__ __forceinline__ void gld_lds16(const void* g, void* l) {
    __builtin_amdgcn_global_load_lds((const __attribute__((address_space(1))) void*)g,
                                     (__attribute__((address_space(3))) void*)l, 16, 0, 0);
}

// ---------------------------------------------------------------------------
// 1) Dequant: W^T[j][k] = lut[j][code(k,j)], bf16, layout (OUT_F, IN_F).
// ---------------------------------------------------------------------------
__global__ __launch_bounds__(256) void k_dequant(const int* __restrict__ qw,
                                                 const float* __restrict__ lut,
                                                 __bf16* __restrict__ Wt) {
    __shared__ int qs[64 * 65];
    __shared__ float ls[64 * 16];
    const int b = blockIdx.x;
    const int jc = (b & 63) * 64;
    const int wc = (b >> 6) * 64;
    const int t = threadIdx.x;

    {
        float4 v = *(const float4*)(lut + (size_t)(jc + (t >> 2)) * 16 + (t & 3) * 4);
        *(float4*)(ls + (t >> 2) * 16 + (t & 3) * 4) = v;
    }
#pragma unroll
    for (int p = 0; p < 4; ++p) {
        int idx = t + p * 256;
        int row = idx >> 4;
        int c4 = (idx & 15) * 4;
        int4 v = *(const int4*)(qw + (size_t)(wc + row) * OUT_F + jc + c4);
        int base = row * 65 + c4;
        qs[base] = v.x; qs[base + 1] = v.y; qs[base + 2] = v.z; qs[base + 3] = v.w;
    }
    __syncthreads();

    const int wave = t >> 6, lane = t & 63;
#pragma unroll
    for (int i = 0; i < 16; ++i) {
        const int c = wave * 16 + i;
        const unsigned q = (unsigned)qs[lane * 65 + c];
        const float* lp = ls + c * 16;
        bf16x8 v;
#pragma unroll
        for (int e = 0; e < 8; ++e) v[e] = (__bf16)lp[(q >> (4 * e)) & 15];
        *(bf16x8*)(Wt + (size_t)(jc + c) * IN_F + (size_t)(wc + lane) * 8) = v;
    }
}

// ---------------------------------------------------------------------------
// 2) CSR outliers, nnz-parallel, word-level CAS (exact).
// ---------------------------------------------------------------------------
__global__ __launch_bounds__(256) void k_csr(const int* __restrict__ rows,
                                             const int* __restrict__ cols,
                                             const float* __restrict__ vals,
                                             __bf16* __restrict__ Wt) {
    int n = blockIdx.x * 256 + threadIdx.x;
    if (n >= NUMVALS) return;
    int lo = 0, hi = OUT_F + 1;
    while (lo < hi) {
        int mid = (lo + hi) >> 1;
        if (rows[mid] <= n) lo = mid + 1; else hi = mid;
    }
    int r = lo - 1;
    int c = cols[n];
    float v = vals[n];
    unsigned* wp = (unsigned*)Wt + (((size_t)r * IN_F + c) >> 1);
    unsigned sh = (c & 1) * 16;
    unsigned old = *wp, assumed;
    do {
        assumed = old;
        union { unsigned u; float f; } cv;
        cv.u = ((assumed >> sh) & 0xFFFFu) << 16;
        __bf16 nb = (__bf16)(cv.f + v);
        unsigned nh = *(unsigned short*)&nb;
        unsigned newv = (assumed & ~(0xFFFFu << sh)) | (nh << sh);
        old = atomicCAS(wp, assumed, newv);
    } while (old != assumed);
}

// ---------------------------------------------------------------------------
// 3) topX dense outlier columns
// ---------------------------------------------------------------------------
__global__ void k_topx(const float* __restrict__ fr, const int* __restrict__ fri,
                       __bf16* __restrict__ Wt) {
    int i = blockIdx.x * 256 + threadIdx.x;
    if (i >= IN_F) return;
#pragma unroll
    for (int t = 0; t < TOPX_N; ++t) {
        int j = fri[t];
        __bf16* p = Wt + (size_t)j * IN_F + i;
        *p = (__bf16)((float)*p + fr[(size_t)i * TOPX_N + t]);
    }
}

// ---------------------------------------------------------------------------
// 4) x fp32 -> bf16
// ---------------------------------------------------------------------------
__global__ void k_cvt(const float* __restrict__ x, __bf16* __restrict__ xb) {
    size_t t = (size_t)blockIdx.x * 256 + threadIdx.x;
    const float4* p = (const float4*)x + 2 * t;
    float4 a = p[0], b = p[1];
    bf16x8 v;
    v[0] = (__bf16)a.x; v[1] = (__bf16)a.y; v[2] = (__bf16)a.z; v[3] = (__bf16)a.w;
    v[4] = (__bf16)b.x; v[5] = (__bf16)b.y; v[6] = (__bf16)b.z; v[7] = (__bf16)b.w;
    ((bf16x8*)xb)[t] = v;
}

// ---------------------------------------------------------------------------
// 5) GEMM, m201-style 8-phase schedule. C(8192x4096) = A * B^T + bias.
//    BM=BN=256, BK=64, 512 thr (8 waves 2Mx4N), per-wave 128x64 out.
//    LDS: 2 bufs x (A 32KB + B 32KB) = 128 KiB. Per K-tile, 4 phases:
//      p0: read af(m0..3)+bf(n0..1)            -> MFMA quad (m0..3 x n0..1)
//      p1: read bf(n2..3)                      -> MFMA quad (m0..3 x n2..3)
//      p2: read af(m4..7); stage B[S+2]        -> MFMA quad (m4..7 x n2..3)
//      p3: stage A[S+2];   vmcnt(8) at end     -> MFMA quad (m4..7 x n0..1)
//    Every stage overwrites LDS >=1 barrier after its last read (B halves
//    freed after p1, A halves after p2). Counted vmcnt(8) keeps tile S+2's
//    8 loads in flight across the tile boundary; only guarantees tile S+1
//    landed (staged a full tile earlier). Never drains to 0 in the loop.
//
//    Swizzle (T2, carried from R1, conflicts measured 0): 16-row x 128B
//    window = 128 slots of 16B; (r,g) at slot P = ((r+g)&7) + 8g + 64(r>>3).
//    Identity P = lane + 64q makes the DMA dest linear (rule #21: linear
//    dest + inverse-swizzled global source + swizzled read).
// ---------------------------------------------------------------------------
#define BK_G 64
#define NKT (IN_F / BK_G)          /* 64 K-tiles */
#define ROWB (IN_F * 2)            /* 8192 B per row */

#define MFMA_ __builtin_amdgcn_mfma_f32_16x16x32_bf16

__global__ __launch_bounds__(512, 2) void k_gemm(const __bf16* __restrict__ A,
                                                 const __bf16* __restrict__ Bt,
                                                 const float* __restrict__ bias,
                                                 float* __restrict__ C) {
    __shared__ __align__(1024) char smem[2][2][32768];   // [buf][A/B] = 128 KiB

    const int tid = threadIdx.x;
    const int v = tid >> 6, l = tid & 63;
    const int wm = v >> 2, wn = v & 3;

    // XCD-aware swizzle: 512 blocks, 8 XCDs, 64 contiguous per XCD.
    const int bid = blockIdx.x;
    const int swz = (bid & 7) * 64 + (bid >> 3);
    const int n0 = (swz & 15) * 256;
    const int m0 = (swz >> 4) * 256;

    // ---- staging map: lane l -> (row r0+8q, granule g) at slot lane+64q ----
    const int g = l >> 3;                  // 0..7 (16B granule in 128B row)
    const int r0 = ((l & 7) - g) & 7;      // row low bits for q=0
    const char* pA = (const char*)A  + (size_t)(m0 + 32 * v + r0) * ROWB + g * 16;
    const char* pB = (const char*)Bt + (size_t)(n0 + 32 * v + r0) * ROWB + g * 16;
    const int ldA = v * 4096;              // wave's 2 windows in A region
    const int ldB = 32768 + v * 4096;      // ... in B region

#define STG(pX, ldX, bo, koff) do {                                              \
        gld_lds16((pX) + (koff),               (char*)smem + (bo) + (ldX));      \
        gld_lds16((pX) + (koff) + 8  * ROWB,   (char*)smem + (bo) + (ldX) + 1024);\
        gld_lds16((pX) + (koff) + 16 * ROWB,   (char*)smem + (bo) + (ldX) + 2048);\
        gld_lds16((pX) + (koff) + 24 * ROWB,   (char*)smem + (bo) + (ldX) + 3072);\
    } while (0)

    // ---- read map: frag (window = wbase + mf, row lrow, granule ks*4+kk) ----
    const int lrow = l & 15, kk = l >> 4;
    const int Pb0 = ((lrow + kk) & 7) * 16 + kk * 128 + (lrow >> 3) * 1024;          // ks=0
    const int Pb1 = ((lrow + kk + 4) & 7) * 16 + (kk + 4) * 128 + (lrow >> 3) * 1024; // ks=1
    const int rdA0 = wm * 16384 + Pb0;
    const int rdA1 = wm * 16384 + Pb1;
    const int rdB0 = 32768 + wn * 8192 + Pb0;
    const int rdB1 = 32768 + wn * 8192 + Pb1;

#define FENCE asm volatile("" ::: "memory")
#define BARRIER do { FENCE; __builtin_amdgcn_s_barrier(); FENCE; } while (0)

    f32x4 acc[8][4] = {};
    bf16x8 af[4][2], bfr[4][2];

    // ---- prologue: tiles 0,1 -> bufs 0,1; wait for tile 0 (8 oldest) ----
    STG(pB, ldB, 0, 0);
    STG(pA, ldA, 0, 0);
    STG(pB, ldB, 65536, 128);
    STG(pA, ldA, 65536, 128);
    asm volatile("s_waitcnt vmcnt(8)" ::: "memory");
    __builtin_amdgcn_s_barrier();
    FENCE;

    for (int S = 0; S < NKT; ++S) {
        const int bo = (S & 1) << 16;
        const int ko = (S + 2) * 128;
        const bool stg = (S < NKT - 2);

        // ---------------- p0: 12 reads -> MFMA (m0..3 x n0..1) ----------------
#pragma unroll
        for (int n = 0; n < 2; ++n) {
            bfr[n][0] = *(const bf16x8*)((const char*)smem + bo + rdB0 + n * 2048);
            bfr[n][1] = *(const bf16x8*)((const char*)smem + bo + rdB1 + n * 2048);
        }
#pragma unroll
        for (int m = 0; m < 4; ++m) {
            af[m][0] = *(const bf16x8*)((const char*)smem + bo + rdA0 + m * 2048);
            af[m][1] = *(const bf16x8*)((const char*)smem + bo + rdA1 + m * 2048);
        }
        BARRIER;
        __builtin_amdgcn_s_setprio(1);
#pragma unroll
        for (int m = 0; m < 4; ++m)
#pragma unroll
            for (int n = 0; n < 2; ++n) {
                acc[m][n] = MFMA_(af[m][0], bfr[n][0], acc[m][n], 0, 0, 0);
                acc[m][n] = MFMA_(af[m][1], bfr[n][1], acc[m][n], 0, 0, 0);
            }
        __builtin_amdgcn_s_setprio(0);
        BARRIER;

        // ---------------- p1: 4 reads -> MFMA (m0..3 x n2..3) ----------------
#pragma unroll
        for (int n = 2; n < 4; ++n) {
            bfr[n][0] = *(const bf16x8*)((const char*)smem + bo + rdB0 + n * 2048);
            bfr[n][1] = *(const bf16x8*)((const char*)smem + bo + rdB1 + n * 2048);
        }
        BARRIER;
        __builtin_amdgcn_s_setprio(1);
#pragma unroll
        for (int m = 0; m < 4; ++m)
#pragma unroll
            for (int n = 2; n < 4; ++n) {
                acc[m][n] = MFMA_(af[m][0], bfr[n][0], acc[m][n], 0, 0, 0);
                acc[m][n] = MFMA_(af[m][1], bfr[n][1], acc[m][n], 0, 0, 0);
            }
        __builtin_amdgcn_s_setprio(0);
        BARRIER;

        // ------- p2: 8 reads (m4..7) + stage B[S+2] -> MFMA (m4..7 x n2..3) -------
#pragma unroll
        for (int m = 0; m < 4; ++m) {
            af[m][0] = *(const bf16x8*)((const char*)smem + bo + rdA0 + (4 + m) * 2048);
            af[m][1] = *(const bf16x8*)((const char*)smem + bo + rdA1 + (4 + m) * 2048);
        }
        if (stg) STG(pB, ldB, bo, ko);
        BARRIER;
        __builtin_amdgcn_s_setprio(1);
#pragma unroll
        for (int m = 0; m < 4; ++m)
#pragma unroll
            for (int n = 2; n < 4; ++n) {
                acc[4 + m][n] = MFMA_(af[m][0], bfr[n][0], acc[4 + m][n], 0, 0, 0);
                acc[4 + m][n] = MFMA_(af[m][1], bfr[n][1], acc[4 + m][n], 0, 0, 0);
            }
        __builtin_amdgcn_s_setprio(0);
        BARRIER;

        // ------- p3: stage A[S+2] -> MFMA (m4..7 x n0..1); counted vmcnt -------
        if (stg) STG(pA, ldA, bo, ko);
        BARRIER;
        __builtin_amdgcn_s_setprio(1);
#pragma unroll
        for (int m = 0; m < 4; ++m)
#pragma unroll
            for (int n = 0; n < 2; ++n) {
                acc[4 + m][n] = MFMA_(af[m][0], bfr[n][0], acc[4 + m][n], 0, 0, 0);
                acc[4 + m][n] = MFMA_(af[m][1], bfr[n][1], acc[4 + m][n], 0, 0, 0);
            }
        __builtin_amdgcn_s_setprio(0);
        if (stg) { asm volatile("s_waitcnt vmcnt(8)" ::: "memory"); }
        else     { asm volatile("s_waitcnt vmcnt(0)" ::: "memory"); }
        __builtin_amdgcn_s_barrier();
        FENCE;
    }

    // ---- epilogue: C/D layout col = lane&15, row = (lane>>4)*4 + r ----
    const int m0w = m0 + wm * 128;
    const int n0w = n0 + wn * 64;
#pragma unroll
    for (int n = 0; n < 4; ++n) {
        const int col = n0w + n * 16 + lrow;
        const float bj = bias[col];
#pragma unroll
        for (int m = 0; m < 8; ++m) {
            const int row = m0w + m * 16 + kk * 4;
#pragma unroll
            for (int r = 0; r < 4; ++r)
                C[(size_t)(row + r) * OUT_F + col] = acc[m][n][r] + bj;
        }
    }
#undef STG
#undef FENCE
#undef BARRIER
}

extern "C" void kernel_launch(void* const* d_in, const int* in_sizes, int n_in,
                              void* d_out, int out_size, void* d_ws, size_t ws_size,
                              hipStream_t stream) {
    const float* x         = (const float*)d_in[0];
    const int*   qweight   = (const int*)d_in[1];
    const float* lut       = (const float*)d_in[2];
    const float* bias      = (const float*)d_in[3];
    const int*   rows      = (const int*)d_in[4];
    const int*   cols      = (const int*)d_in[5];
    const float* vals      = (const float*)d_in[6];
    const float* full_rows = (const float*)d_in[7];
    const int*   fri       = (const int*)d_in[8];
    float* out = (float*)d_out;

    __bf16* Wt = (__bf16*)d_ws;                                        // 32 MB: W^T (OUT_F, IN_F)
    __bf16* xb = (__bf16*)((char*)d_ws + (size_t)OUT_F * IN_F * 2);    // 64 MB: x bf16 (8192, 4096)

    k_dequant<<<dim3(64 * 8), 256, 0, stream>>>(qweight, lut, Wt);
    k_csr<<<dim3((NUMVALS + 255) / 256), 256, 0, stream>>>(rows, cols, vals, Wt);
    k_topx<<<dim3(IN_F / 256), 256, 0, stream>>>(full_rows, fri, Wt);
    k_cvt<<<dim3((size_t)MTOK * IN_F / 8 / 256), 256, 0, stream>>>(x, xb);
    k_gemm<<<dim3((OUT_F / 256) * (MTOK / 256)), 512, 0, stream>>>(xb, Wt, bias, out);
}